// Round 5
// baseline (1200.150 us; speedup 1.0000x reference)
//
#include <hip/hip_runtime.h>

typedef unsigned short u16;
typedef short short8v __attribute__((ext_vector_type(8)));
typedef float float4v __attribute__((ext_vector_type(4)));

__device__ __forceinline__ float b2f(u16 u) { return __uint_as_float(((unsigned)u) << 16); }
__device__ __forceinline__ u16 f2b(float f) {
    unsigned i = __float_as_uint(f);
    unsigned r = i + 0x7fffu + ((i >> 16) & 1u);
    return (u16)(r >> 16);
}
__device__ __forceinline__ float gelu_f(float x) {
    float x3 = x * x * x;
    return 0.5f * x * (1.0f + tanhf(0.7978845608028654f * (x + 0.044715f * x3)));
}

// out[n*K + k] = bf16(in[k*N + n])   (fp32 weights -> bf16 transposed, k-contiguous)
__global__ void transpose_k(const float* __restrict__ in, u16* __restrict__ out, int K, int N) {
    int idx = blockIdx.x * 256 + threadIdx.x;
    if (idx < K * N) {
        int n = idx / K;
        int k = idx - n * K;
        out[idx] = f2b(in[(size_t)k * N + n]);
    }
}

// LN1 + cyclic shift(-3,-3) + window partition. One wave per windowed token (chunk-local).
__global__ __launch_bounds__(256) void ln1_win_kernel(
    const float* __restrict__ x, size_t tok0, const float* __restrict__ sc,
    const float* __restrict__ bi, u16* __restrict__ win) {
    int t = blockIdx.x * 4 + (threadIdx.x >> 6);
    int lane = threadIdx.x & 63;
    int wi = t / 49, p = t - wi * 49;
    int b = wi >> 6, w = wi & 63;
    int wr = w >> 3, wc = w & 7;
    int ii = p / 7, jj = p - ii * 7;
    int r = wr * 7 + ii + 3; if (r >= 56) r -= 56;
    int c = wc * 7 + jj + 3; if (c >= 56) c -= 56;
    size_t off = (tok0 + (size_t)(b * 3136 + r * 56 + c)) * 256 + lane * 4;
    float4 d = *(const float4*)(x + off);
    float v0 = d.x, v1 = d.y, v2 = d.z, v3 = d.w;
    float s = v0 + v1 + v2 + v3;
    float ss = v0 * v0 + v1 * v1 + v2 * v2 + v3 * v3;
#pragma unroll
    for (int o = 32; o; o >>= 1) { s += __shfl_xor(s, o, 64); ss += __shfl_xor(ss, o, 64); }
    float mu = s * (1.0f / 256.0f);
    float rs = rsqrtf(ss * (1.0f / 256.0f) - mu * mu + 1e-6f);
    float4 s4 = *(const float4*)(sc + lane * 4);
    float4 b4 = *(const float4*)(bi + lane * 4);
    ushort4 o4;
    o4.x = f2b((v0 - mu) * rs * s4.x + b4.x);
    o4.y = f2b((v1 - mu) * rs * s4.y + b4.y);
    o4.z = f2b((v2 - mu) * rs * s4.z + b4.z);
    o4.w = f2b((v3 - mu) * rs * s4.w + b4.w);
    *(ushort4*)(win + (size_t)t * 256 + lane * 4) = o4;
}

// C[M,N] = A[M,K] @ Bt[N,K]^T + bias(fp32), M-guarded. A/Bt bf16.
// EPI: 0 = bias (bf16 out), 1 = bias+gelu (bf16 out), 2 = bias+residual (FP32 out).
template <int EPI>
__global__ __launch_bounds__(256) void gemm_bt(
    const u16* __restrict__ A, const u16* __restrict__ Bt, const float* __restrict__ bias,
    const u16* __restrict__ res, void* __restrict__ Cout, int M, int N, int K) {
    __shared__ __align__(16) u16 As[128][72];  // +8 pad: 2-way ds conflict only (free)
    __shared__ __align__(16) u16 Bs[128][72];
    int tid = threadIdx.x;
    int m0 = blockIdx.x * 128, n0 = blockIdx.y * 128;
    int lane = tid & 63, wave = tid >> 6;
    int wm = (wave >> 1) * 64, wn = (wave & 1) * 64;
    int lrow = lane & 15, qd = lane >> 4;
    float4v acc[4][4] = {};
    int kTiles = K >> 6;
    for (int kt = 0; kt < kTiles; ++kt) {
        int k0 = kt << 6;
#pragma unroll
        for (int cc = 0; cc < 4; ++cc) {
            int id = tid + cc * 256;
            int row = id >> 3, ko = (id & 7) << 3;
            int rA = m0 + row; if (rA >= M) rA = M - 1;  // clamp; value unused (store guarded)
            *(uint4*)&As[row][ko] = *(const uint4*)(A + (size_t)rA * K + (k0 + ko));
            *(uint4*)&Bs[row][ko] = *(const uint4*)(Bt + (size_t)(n0 + row) * K + (k0 + ko));
        }
        __syncthreads();
#pragma unroll
        for (int ks = 0; ks < 64; ks += 32) {
            short8v af[4], bfr[4];
#pragma unroll
            for (int mi = 0; mi < 4; ++mi)
                af[mi] = *(const short8v*)&As[wm + mi * 16 + lrow][ks + qd * 8];
#pragma unroll
            for (int ni = 0; ni < 4; ++ni)
                bfr[ni] = *(const short8v*)&Bs[wn + ni * 16 + lrow][ks + qd * 8];
#pragma unroll
            for (int mi = 0; mi < 4; ++mi)
#pragma unroll
                for (int ni = 0; ni < 4; ++ni)
                    acc[mi][ni] = __builtin_amdgcn_mfma_f32_16x16x32_bf16(
                        af[mi], bfr[ni], acc[mi][ni], 0, 0, 0);
        }
        __syncthreads();
    }
#pragma unroll
    for (int ni = 0; ni < 4; ++ni) {
        int col = n0 + wn + ni * 16 + lrow;
        float bv = bias[col];
#pragma unroll
        for (int mi = 0; mi < 4; ++mi) {
#pragma unroll
            for (int rr = 0; rr < 4; ++rr) {
                int row = m0 + wm + mi * 16 + qd * 4 + rr;
                if (row < M) {
                    float v = acc[mi][ni][rr] + bv;
                    if (EPI == 1) v = gelu_f(v);
                    if (EPI == 2) {
                        v += b2f(res[(size_t)row * N + col]);
                        ((float*)Cout)[(size_t)row * N + col] = v;   // fp32 final output
                    } else {
                        ((u16*)Cout)[(size_t)row * N + col] = f2b(v);
                    }
                }
            }
        }
    }
}

// One wave per (window-in-chunk, head). q in regs, k/v in LDS (fp32, broadcast reads).
__global__ __launch_bounds__(256) void attn_kernel(
    const u16* __restrict__ qkv, const float* __restrict__ btab, u16* __restrict__ attno) {
    __shared__ float kvs[4][2][49][32];  // 50176 B
    int wave = threadIdx.x >> 6, lane = threadIdx.x & 63;
    int u = blockIdx.x * 4 + wave;
    int wi = u >> 3, h = u & 7;
    int w = wi & 63;                      // window-within-batch (mask depends only on this)
    const u16* base = qkv + (size_t)wi * 49 * 768 + h * 32;
    for (int idx = lane; idx < 196; idx += 64) {
        int p = idx >> 2, part = (idx & 3) << 3;
        uint4 kd = *(const uint4*)(base + 256 + (size_t)p * 768 + part);
        uint4 vd = *(const uint4*)(base + 512 + (size_t)p * 768 + part);
        float* kp = &kvs[wave][0][p][part];
        float* vp = &kvs[wave][1][p][part];
        const unsigned* ku = (const unsigned*)&kd;
        const unsigned* vu = (const unsigned*)&vd;
#pragma unroll
        for (int i = 0; i < 4; ++i) {
            kp[2 * i] = __uint_as_float(ku[i] << 16);
            kp[2 * i + 1] = __uint_as_float(ku[i] & 0xffff0000u);
            vp[2 * i] = __uint_as_float(vu[i] << 16);
            vp[2 * i + 1] = __uint_as_float(vu[i] & 0xffff0000u);
        }
    }
    __syncthreads();
    int p = lane;
    if (p < 49) {
        float qreg[32];
        const u16* qp = base + (size_t)p * 768;
#pragma unroll
        for (int cq = 0; cq < 4; ++cq) {
            uint4 qd = *(const uint4*)(qp + cq * 8);
            const unsigned* qu = (const unsigned*)&qd;
#pragma unroll
            for (int i = 0; i < 4; ++i) {
                qreg[cq * 8 + 2 * i] = __uint_as_float(qu[i] << 16);
                qreg[cq * 8 + 2 * i + 1] = __uint_as_float(qu[i] & 0xffff0000u);
            }
        }
        int wrr = (w >> 3) * 7, wcc = (w & 7) * 7;
        int py = p / 7, px = p - py * 7;
        int rp = wrr + py, cp = wcc + px;
        int regp = (rp < 49 ? 0 : (rp < 53 ? 1 : 2)) * 3 + (cp < 49 ? 0 : (cp < 53 ? 1 : 2));
        float sreg[49];
        const float scale = 0.17677669529663687f;  // 32^-0.5
#pragma unroll
        for (int q = 0; q < 49; ++q) {
            const float4* krow = (const float4*)kvs[wave][0][q];
            float s = 0.f;
#pragma unroll
            for (int d4 = 0; d4 < 8; ++d4) {
                float4 kk = krow[d4];
                s += qreg[d4 * 4] * kk.x + qreg[d4 * 4 + 1] * kk.y +
                     qreg[d4 * 4 + 2] * kk.z + qreg[d4 * 4 + 3] * kk.w;
            }
            s *= scale;
            int qy = q / 7, qx = q - qy * 7;
            int ridx = (px - qx + 6) * 13 + (py - qy + 6);
            s += btab[ridx * 8 + h];
            int rq = wrr + qy, cq2 = wcc + qx;
            int regq = (rq < 49 ? 0 : (rq < 53 ? 1 : 2)) * 3 + (cq2 < 49 ? 0 : (cq2 < 53 ? 1 : 2));
            s += (regq != regp) ? -100.f : 0.f;
            sreg[q] = s;
        }
        float mx = sreg[0];
#pragma unroll
        for (int q = 1; q < 49; ++q) mx = fmaxf(mx, sreg[q]);
        float sum = 0.f;
#pragma unroll
        for (int q = 0; q < 49; ++q) { float e = __expf(sreg[q] - mx); sreg[q] = e; sum += e; }
        float inv = 1.0f / sum;
        float acc[32];
#pragma unroll
        for (int i = 0; i < 32; ++i) acc[i] = 0.f;
#pragma unroll
        for (int q = 0; q < 49; ++q) {
            float pv = sreg[q] * inv;
            const float4* vrow = (const float4*)kvs[wave][1][q];
#pragma unroll
            for (int d4 = 0; d4 < 8; ++d4) {
                float4 vv = vrow[d4];
                acc[d4 * 4] += pv * vv.x;
                acc[d4 * 4 + 1] += pv * vv.y;
                acc[d4 * 4 + 2] += pv * vv.z;
                acc[d4 * 4 + 3] += pv * vv.w;
            }
        }
        u16* op = attno + ((size_t)wi * 49 + p) * 256 + h * 32;
#pragma unroll
        for (int cq = 0; cq < 4; ++cq) {
            uint4 dd;
            unsigned* dp = (unsigned*)&dd;
#pragma unroll
            for (int i = 0; i < 4; ++i)
                dp[i] = (unsigned)f2b(acc[cq * 8 + 2 * i]) |
                        ((unsigned)f2b(acc[cq * 8 + 2 * i + 1]) << 16);
            *(uint4*)(op + cq * 8) = dd;
        }
    }
}

// window reverse + roll(+3,+3) + residual + LN2. One wave per natural token (chunk-local).
__global__ __launch_bounds__(256) void scatter_ln2_kernel(
    const float* __restrict__ x, size_t tok0, const u16* __restrict__ projo,
    const float* __restrict__ sc, const float* __restrict__ bi,
    u16* __restrict__ x2, u16* __restrict__ ln2o) {
    int tk = blockIdx.x * 4 + (threadIdx.x >> 6);
    int lane = threadIdx.x & 63;
    int b = tk / 3136, l = tk - b * 3136;
    int r = l / 56, c = l - r * 56;
    int r2 = r + 53; if (r2 >= 56) r2 -= 56;
    int c2 = c + 53; if (c2 >= 56) c2 -= 56;
    int wr = r2 / 7, ri = r2 - wr * 7;
    int wc = c2 / 7, ci = c2 - wc * 7;
    size_t t = ((size_t)(b * 64 + wr * 8 + wc)) * 49 + ri * 7 + ci;
    size_t loff = (size_t)tk * 256 + lane * 4;
    size_t goff = (tok0 + tk) * 256 + lane * 4;
    float4 xd = *(const float4*)(x + goff);
    ushort4 pd = *(const ushort4*)(projo + t * 256 + lane * 4);
    float v0 = xd.x + b2f(pd.x);
    float v1 = xd.y + b2f(pd.y);
    float v2 = xd.z + b2f(pd.z);
    float v3 = xd.w + b2f(pd.w);
    ushort4 o4;
    o4.x = f2b(v0); o4.y = f2b(v1); o4.z = f2b(v2); o4.w = f2b(v3);
    *(ushort4*)(x2 + loff) = o4;
    float s = v0 + v1 + v2 + v3;
    float ss = v0 * v0 + v1 * v1 + v2 * v2 + v3 * v3;
#pragma unroll
    for (int o = 32; o; o >>= 1) { s += __shfl_xor(s, o, 64); ss += __shfl_xor(ss, o, 64); }
    float mu = s * (1.0f / 256.0f);
    float rs = rsqrtf(ss * (1.0f / 256.0f) - mu * mu + 1e-6f);
    float4 s4 = *(const float4*)(sc + lane * 4);
    float4 b4 = *(const float4*)(bi + lane * 4);
    ushort4 n4;
    n4.x = f2b((v0 - mu) * rs * s4.x + b4.x);
    n4.y = f2b((v1 - mu) * rs * s4.y + b4.y);
    n4.z = f2b((v2 - mu) * rs * s4.z + b4.z);
    n4.w = f2b((v3 - mu) * rs * s4.w + b4.w);
    *(ushort4*)(ln2o + loff) = n4;
}

extern "C" void kernel_launch(void* const* d_in, const int* in_sizes, int n_in,
                              void* d_out, int out_size, void* d_ws, size_t ws_size,
                              hipStream_t stream) {
    const float* x     = (const float*)d_in[0];
    const float* ln1s  = (const float*)d_in[1];
    const float* ln1b  = (const float*)d_in[2];
    const float* qkvw  = (const float*)d_in[3];
    const float* qkvb  = (const float*)d_in[4];
    const float* projw = (const float*)d_in[5];
    const float* projb = (const float*)d_in[6];
    const float* btab  = (const float*)d_in[7];
    const float* ln2s  = (const float*)d_in[8];
    const float* ln2b  = (const float*)d_in[9];
    const float* fc1w  = (const float*)d_in[10];
    const float* fc1b  = (const float*)d_in[11];
    const float* fc2w  = (const float*)d_in[12];
    const float* fc2b  = (const float*)d_in[13];
    float* out = (float*)d_out;                 // FINAL OUTPUT IS FP32
    char* ws = (char*)d_ws;

    // ws: transposed bf16 weights (1.5 MB), then chunk regions.
    u16* wt_qkv  = (u16*)(ws + 0);        // 256x768^T   393216 B
    u16* wt_proj = (u16*)(ws + 393216);   // 256x256^T   131072 B
    u16* wt_fc1  = (u16*)(ws + 524288);   // 256x1024^T  524288 B
    u16* wt_fc2  = (u16*)(ws + 1048576);  // 1024x256^T  524288 B
    const size_t base = 1572864;

    transpose_k<<<768, 256, 0, stream>>>(qkvw, wt_qkv, 256, 768);
    transpose_k<<<256, 256, 0, stream>>>(projw, wt_proj, 256, 256);
    transpose_k<<<1024, 256, 0, stream>>>(fc1w, wt_fc1, 256, 1024);
    transpose_k<<<1024, 256, 0, stream>>>(fc2w, wt_fc2, 1024, 256);

    // chunk size NB (batches): footprint = base + T*3072 B, T = NB*3136 tokens; floor NB=1
    int NB = 32;
    while (NB > 1 && base + (size_t)NB * 3136 * 3072 > ws_size) NB >>= 1;
    const size_t T = (size_t)NB * 3136;

    u16* regA = (u16*)(ws + base);                       // T*512  B: win -> attno -> ln2o
    u16* regB = (u16*)(ws + base + T * 512);             // T*2048 B: qkv -> projo -> mlph
    u16* regX = (u16*)(ws + base + T * 512 + T * 2048);  // T*512  B: x2 residual

    for (int c0 = 0; c0 < 32; c0 += NB) {
        size_t tok0 = (size_t)c0 * 3136;
        float* outc = out + tok0 * 256;
        int Mc = (int)T;
        int gx = (Mc + 127) / 128;

        ln1_win_kernel<<<Mc / 4, 256, 0, stream>>>(x, tok0, ln1s, ln1b, regA);
        gemm_bt<0><<<dim3(gx, 6), 256, 0, stream>>>(regA, wt_qkv, qkvb, nullptr,
                                                    regB, Mc, 768, 256);
        attn_kernel<<<NB * 128, 256, 0, stream>>>(regB, btab, regA);
        gemm_bt<0><<<dim3(gx, 2), 256, 0, stream>>>(regA, wt_proj, projb, nullptr,
                                                    regB, Mc, 256, 256);
        scatter_ln2_kernel<<<Mc / 4, 256, 0, stream>>>(x, tok0, regB, ln2s, ln2b,
                                                       regX, regA);
        gemm_bt<1><<<dim3(gx, 8), 256, 0, stream>>>(regA, wt_fc1, fc1b, nullptr,
                                                    regB, Mc, 1024, 256);
        gemm_bt<2><<<dim3(gx, 2), 256, 0, stream>>>(regB, wt_fc2, fc2b, regX,
                                                    outc, Mc, 256, 1024);
    }
}